// Round 27
// baseline (78.283 us; speedup 1.0000x reference)
//
#include <hip/hip_runtime.h>
#include <hip/hip_bf16.h>
#include <math.h>

#define B_ 4
#define T_ 4096
#define E_ 1024
#define H_ 64
#define KFB (T_ * H_)   // shorts per batch in Kf/Vf (fragment-major)
#define PRJ_RS2 524  // LDS row stride in shorts (1048B): 16B-aligned, 2-way banks

using bf16x8 = __attribute__((ext_vector_type(8))) short;
using f32x4  = __attribute__((ext_vector_type(4))) float;

__device__ inline short f2bf_rn(float f) {
  return (short)((__builtin_bit_cast(unsigned, f) + 0x8000u) >> 16);
}
__device__ inline unsigned pack2(float a, float b) {
  const unsigned ua = __builtin_bit_cast(unsigned, a) + 0x8000u;
  const unsigned ub = __builtin_bit_cast(unsigned, b) + 0x8000u;
  return (ua >> 16) | (ub & 0xFFFF0000u);
}
__device__ inline float bf2f(short s) {
  unsigned u = ((unsigned)(unsigned short)s) << 16;
  return __builtin_bit_cast(float, u);
}

// ---------- wt fragment-major: wtf[n][ks][lane][8] = W[32ks+8g+e][(n&3)*16+l15]
__global__ __launch_bounds__(256)
void wtconv_kernel(const float* __restrict__ wq, const float* __restrict__ wk,
                   const float* __restrict__ wv, short* __restrict__ wtf) {
  const int t = threadIdx.x;
  const int lane = t & 63, g = lane >> 4, l15 = lane & 15;
  const int ks = (blockIdx.x & 7) * 4 + (t >> 6);
  const int n = blockIdx.x >> 3;           // 0..11
  const float* W = (n < 4) ? wq : (n < 8) ? wk : wv;
  const int h = (n & 3) * 16 + l15;
  const int kbase = 32 * ks + 8 * g;
  bf16x8 v;
#pragma unroll
  for (int e = 0; e < 8; ++e) v[e] = f2bf_rn(W[(size_t)(kbase + e) * H_ + h]);
  *(bf16x8*)&wtf[((size_t)(n * 32 + ks) * 64 + lane) * 8] = v;
}

// ---------- QKV projection v11: K-phased LDS (33.5KB -> 4 blocks/CU) ----------
// 32q block, 256 thr = 4 waves (col-triples). Stage 512 x-cols, sync, 16
// k-steps, sync, restage remaining 512 cols, 16 more steps. Each wave
// accumulates all K itself (no reduce); 4 blocks/CU pipeline stage vs compute.
__global__ __launch_bounds__(256)
void proj_kernel(const float* __restrict__ x, const short* __restrict__ wtf,
                 short* __restrict__ Qb, short* __restrict__ Kb,
                 short* __restrict__ Vt) {
  __shared__ short xs[32 * PRJ_RS2];
  const int q0 = blockIdx.x * 32;
  const int t = threadIdx.x;
  const int w = t >> 6, lane = t & 63, g = lane >> 4, l15 = lane & 15;
  f32x4 acc[6] = {{0,0,0,0},{0,0,0,0},{0,0,0,0},{0,0,0,0},{0,0,0,0},{0,0,0,0}};
#pragma unroll
  for (int half = 0; half < 2; ++half) {
    {
      const float4* xsrc = (const float4*)(x + (size_t)q0 * E_ + half * 512);
#pragma unroll
      for (int j = 0; j < 16; ++j) {
        const int i = t + 256 * j;        // 4096 float4s = 32 rows x 128
        const int row = i >> 7, col4 = i & 127;
        const float4 v = xsrc[(size_t)row * 256 + col4];
        uint2 u;
        u.x = pack2(v.x, v.y);
        u.y = pack2(v.z, v.w);
        *(uint2*)&xs[row * PRJ_RS2 + col4 * 4] = u;
      }
    }
    __syncthreads();
    const short* xr0 = &xs[l15 * PRJ_RS2 + 8 * g];
    const short* xr1 = &xs[(16 + l15) * PRJ_RS2 + 8 * g];
    const int ksbase = half * 16;
#pragma unroll 4
    for (int ks = 0; ks < 16; ++ks) {
      const bf16x8 av0 = *(const bf16x8*)(xr0 + ks * 32);
      const bf16x8 av1 = *(const bf16x8*)(xr1 + ks * 32);
      const short* wp =
          wtf + ((size_t)(w * 3 * 32 + ksbase + ks) * 64 + lane) * 8;
#pragma unroll
      for (int n = 0; n < 3; ++n) {
        const bf16x8 bfr = *(const bf16x8*)(wp + (size_t)n * 32 * 64 * 8);
        acc[n]     = __builtin_amdgcn_mfma_f32_16x16x32_bf16(av0, bfr, acc[n], 0, 0, 0);
        acc[3 + n] = __builtin_amdgcn_mfma_f32_16x16x32_bf16(av1, bfr, acc[3 + n], 0, 0, 0);
      }
    }
    __syncthreads();                      // before restaging overwrites xs
  }
#pragma unroll
  for (int sub = 0; sub < 2; ++sub) {
#pragma unroll
    for (int n = 0; n < 3; ++n) {
      const int ntg = w * 3 + n;
      const int mat = ntg >> 2;
      const int h = (ntg & 3) * 16 + l15;
#pragma unroll
      for (int r = 0; r < 4; ++r) {
        const int q = q0 + sub * 16 + 4 * g + r;
        const short v = f2bf_rn(acc[3 * sub + n][r]);
        if (mat == 0)      Qb[(size_t)q * H_ + h] = v;
        else if (mat == 1) Kb[(size_t)q * H_ + h] = v;
        else               Vt[((size_t)(q >> 12) * H_ + h) * T_ + (q & (T_ - 1))] = v;
      }
    }
  }
}

// ---------- repack K,V into fragment-major Kf, Vf ----------
__global__ __launch_bounds__(256)
void repack_kernel(const short* __restrict__ Kb, const short* __restrict__ Vt,
                   short* __restrict__ Kf, short* __restrict__ Vf) {
  const int s = blockIdx.x, b = blockIdx.y;
  const int t = threadIdx.x;
  const int lane = t & 63, g = lane >> 4, l15 = lane & 15, slot = t >> 6;
  const int sig = ((l15 >> 2) << 3) + (l15 & 3);
  const size_t dst = ((size_t)b * KFB) + (((size_t)s * 4 + slot) * 64 + lane) * 8;
  const int key = 32 * s + sig + 4 * (slot >> 1);
  const int colK = (slot & 1) * 32 + 8 * g;
  *(bf16x8*)&Kf[dst] =
      *(const bf16x8*)&Kb[((size_t)b * T_ + key) * H_ + colK];
  *(bf16x8*)&Vf[dst] =
      *(const bf16x8*)&Vt[((size_t)b * H_ + slot * 16 + l15) * T_ + 32 * s + 8 * g];
}

// ---------- fused attention v9: complementary-pair grid + phase-1 2-wide -----
__global__ __launch_bounds__(512, 4)
void attn_fused_kernel(const short* __restrict__ Qb, const short* __restrict__ Kf,
                       const short* __restrict__ Vf, float* __restrict__ out) {
  __shared__ float osh[4][32][68];
  __shared__ float zsh[8][32];
  __shared__ float wsh[4][32];
  const int i = blockIdx.x;                 // 0..511
  const int hi = i >> 8;                    // 0/1
  const int b = (i & 1) | (hi << 1);        // 0..3
  const int j = (i >> 1) & 127;
  const int qt = hi ? j : 127 - j;          // i and i+256: complementary qt
  const int q0 = qt * 32;

  const int t = threadIdx.x;
  const int w = t >> 6, lane = t & 63, g = lane >> 4, l15 = lane & 15;
  const short* Qp = Qb + (size_t)b * T_ * H_;
  const short* kfB = Kf + (size_t)b * KFB;
  const short* vfB = Vf + (size_t)b * KFB;
  const size_t lo8 = (size_t)lane * 8;

  bf16x8 aq[2][2];
#pragma unroll
  for (int qs = 0; qs < 2; ++qs)
#pragma unroll
    for (int h = 0; h < 2; ++h)
      aq[qs][h] = *(const bf16x8*)&Qp[(size_t)(q0 + qs*16 + l15) * H_ + h*32 + 8*g];

  // ---- phase 1: Z over all keys, 2 chunks per body (wave stride 512) ----
  float z[2] = {0.f, 0.f};
  for (int kt = w * 32; kt < T_; kt += 512) {
    const short* ka = kfB + ((size_t)(kt >> 5) * 2048) + lo8;
    const short* kb2 = kfB + ((size_t)((kt + 256) >> 5) * 2048) + lo8;
    const bf16x8 a00 = *(const bf16x8*)(ka);
    const bf16x8 a01 = *(const bf16x8*)(ka + 512);
    const bf16x8 a10 = *(const bf16x8*)(ka + 1024);
    const bf16x8 a11 = *(const bf16x8*)(ka + 1536);
    const bf16x8 b00 = *(const bf16x8*)(kb2);
    const bf16x8 b01 = *(const bf16x8*)(kb2 + 512);
    const bf16x8 b10 = *(const bf16x8*)(kb2 + 1024);
    const bf16x8 b11 = *(const bf16x8*)(kb2 + 1536);
    f32x4 sA0 = {0,0,0,0}, sA1 = {0,0,0,0}, sA2 = {0,0,0,0}, sA3 = {0,0,0,0};
    f32x4 sB0 = {0,0,0,0}, sB1 = {0,0,0,0}, sB2 = {0,0,0,0}, sB3 = {0,0,0,0};
    sA0 = __builtin_amdgcn_mfma_f32_16x16x32_bf16(a00, aq[0][0], sA0, 0,0,0);
    sA0 = __builtin_amdgcn_mfma_f32_16x16x32_bf16(a01, aq[0][1], sA0, 0,0,0);
    sA1 = __builtin_amdgcn_mfma_f32_16x16x32_bf16(a10, aq[0][0], sA1, 0,0,0);
    sA1 = __builtin_amdgcn_mfma_f32_16x16x32_bf16(a11, aq[0][1], sA1, 0,0,0);
    sA2 = __builtin_amdgcn_mfma_f32_16x16x32_bf16(a00, aq[1][0], sA2, 0,0,0);
    sA2 = __builtin_amdgcn_mfma_f32_16x16x32_bf16(a01, aq[1][1], sA2, 0,0,0);
    sA3 = __builtin_amdgcn_mfma_f32_16x16x32_bf16(a10, aq[1][0], sA3, 0,0,0);
    sA3 = __builtin_amdgcn_mfma_f32_16x16x32_bf16(a11, aq[1][1], sA3, 0,0,0);
    sB0 = __builtin_amdgcn_mfma_f32_16x16x32_bf16(b00, aq[0][0], sB0, 0,0,0);
    sB0 = __builtin_amdgcn_mfma_f32_16x16x32_bf16(b01, aq[0][1], sB0, 0,0,0);
    sB1 = __builtin_amdgcn_mfma_f32_16x16x32_bf16(b10, aq[0][0], sB1, 0,0,0);
    sB1 = __builtin_amdgcn_mfma_f32_16x16x32_bf16(b11, aq[0][1], sB1, 0,0,0);
    sB2 = __builtin_amdgcn_mfma_f32_16x16x32_bf16(b00, aq[1][0], sB2, 0,0,0);
    sB2 = __builtin_amdgcn_mfma_f32_16x16x32_bf16(b01, aq[1][1], sB2, 0,0,0);
    sB3 = __builtin_amdgcn_mfma_f32_16x16x32_bf16(b10, aq[1][0], sB3, 0,0,0);
    sB3 = __builtin_amdgcn_mfma_f32_16x16x32_bf16(b11, aq[1][1], sB3, 0,0,0);
#pragma unroll
    for (int r = 0; r < 4; ++r) {
      z[0] += __expf(sA0[r] * 0.125f) + __expf(sA1[r] * 0.125f) +
              __expf(sB0[r] * 0.125f) + __expf(sB1[r] * 0.125f);
      z[1] += __expf(sA2[r] * 0.125f) + __expf(sA3[r] * 0.125f) +
              __expf(sB2[r] * 0.125f) + __expf(sB3[r] * 0.125f);
    }
  }
#pragma unroll
  for (int qs = 0; qs < 2; ++qs) {
    float v = z[qs];
    v += __shfl_xor(v, 16);
    v += __shfl_xor(v, 32);
    z[qs] = v;
  }
  if (lane < 16) {
    zsh[w][l15] = z[0];
    zsh[w][16 + l15] = z[1];
  }
  __syncthreads();
  float zinv[2];
#pragma unroll
  for (int qs = 0; qs < 2; ++qs) {
    float zsum = 0.f;
#pragma unroll
    for (int ww = 0; ww < 8; ++ww) zsum += zsh[ww][qs * 16 + l15];
    zinv[qs] = 1.0f / zsum;
  }

  // ---- phase 2: causal keys, wave stride 256 ----
  f32x4 o[2][4] = {{{0,0,0,0},{0,0,0,0},{0,0,0,0},{0,0,0,0}},
                   {{0,0,0,0},{0,0,0,0},{0,0,0,0},{0,0,0,0}}};
  float ws[2] = {0.f, 0.f};
  const int kend = q0 + 32;
  for (int kt = w * 32; kt < kend; kt += 256) {
    const size_t sb = ((size_t)(kt >> 5) * 2048) + lo8;
    const short* kb = kfB + sb;
    const bf16x8 ak00 = *(const bf16x8*)(kb);
    const bf16x8 ak01 = *(const bf16x8*)(kb + 512);
    const bf16x8 ak10 = *(const bf16x8*)(kb + 1024);
    const bf16x8 ak11 = *(const bf16x8*)(kb + 1536);
    const short* vb = vfB + sb;
    const bf16x8 av0 = *(const bf16x8*)(vb);
    const bf16x8 av1 = *(const bf16x8*)(vb + 512);
    const bf16x8 av2 = *(const bf16x8*)(vb + 1024);
    const bf16x8 av3 = *(const bf16x8*)(vb + 1536);

    bf16x8 wb[2];
    if (kt + 31 < q0) {                     // interior: all keys < all q
#pragma unroll
      for (int qs = 0; qs < 2; ++qs) {
        f32x4 sA = {0,0,0,0}, sB = {0,0,0,0};
        sA = __builtin_amdgcn_mfma_f32_16x16x32_bf16(ak00, aq[qs][0], sA, 0,0,0);
        sA = __builtin_amdgcn_mfma_f32_16x16x32_bf16(ak01, aq[qs][1], sA, 0,0,0);
        sB = __builtin_amdgcn_mfma_f32_16x16x32_bf16(ak10, aq[qs][0], sB, 0,0,0);
        sB = __builtin_amdgcn_mfma_f32_16x16x32_bf16(ak11, aq[qs][1], sB, 0,0,0);
        const float zi = zinv[qs];
        float wsl = 0.f;
#pragma unroll
        for (int r = 0; r < 4; ++r) {
          const float w0 = __expf(__expf(sA[r] * 0.125f) * zi);
          const float w1 = __expf(__expf(sB[r] * 0.125f) * zi);
          wsl += w0 + w1;
          wb[qs][r] = f2bf_rn(w0);
          wb[qs][4 + r] = f2bf_rn(w1);
        }
        ws[qs] += wsl;
      }
    } else {                                // diagonal: per-element mask
#pragma unroll
      for (int qs = 0; qs < 2; ++qs) {
        f32x4 sA = {0,0,0,0}, sB = {0,0,0,0};
        sA = __builtin_amdgcn_mfma_f32_16x16x32_bf16(ak00, aq[qs][0], sA, 0,0,0);
        sA = __builtin_amdgcn_mfma_f32_16x16x32_bf16(ak01, aq[qs][1], sA, 0,0,0);
        sB = __builtin_amdgcn_mfma_f32_16x16x32_bf16(ak10, aq[qs][0], sB, 0,0,0);
        sB = __builtin_amdgcn_mfma_f32_16x16x32_bf16(ak11, aq[qs][1], sB, 0,0,0);
        const int qg = q0 + qs * 16 + l15;
        const float zi = zinv[qs];
        float wsl = 0.f;
#pragma unroll
        for (int r = 0; r < 4; ++r) {
          const int key0 = kt + 8 * g + r;
          const float w0 = (key0     <= qg) ? __expf(__expf(sA[r] * 0.125f) * zi) : 0.f;
          const float w1 = (key0 + 4 <= qg) ? __expf(__expf(sB[r] * 0.125f) * zi) : 0.f;
          wsl += w0 + w1;
          wb[qs][r] = f2bf_rn(w0);
          wb[qs][4 + r] = f2bf_rn(w1);
        }
        ws[qs] += wsl;
      }
    }
    o[0][0] = __builtin_amdgcn_mfma_f32_16x16x32_bf16(av0, wb[0], o[0][0], 0,0,0);
    o[0][1] = __builtin_amdgcn_mfma_f32_16x16x32_bf16(av1, wb[0], o[0][1], 0,0,0);
    o[0][2] = __builtin_amdgcn_mfma_f32_16x16x32_bf16(av2, wb[0], o[0][2], 0,0,0);
    o[0][3] = __builtin_amdgcn_mfma_f32_16x16x32_bf16(av3, wb[0], o[0][3], 0,0,0);
    o[1][0] = __builtin_amdgcn_mfma_f32_16x16x32_bf16(av0, wb[1], o[1][0], 0,0,0);
    o[1][1] = __builtin_amdgcn_mfma_f32_16x16x32_bf16(av1, wb[1], o[1][1], 0,0,0);
    o[1][2] = __builtin_amdgcn_mfma_f32_16x16x32_bf16(av2, wb[1], o[1][2], 0,0,0);
    o[1][3] = __builtin_amdgcn_mfma_f32_16x16x32_bf16(av3, wb[1], o[1][3], 0,0,0);
  }

#pragma unroll
  for (int qs = 0; qs < 2; ++qs) {
    float v = ws[qs];
    v += __shfl_xor(v, 16);
    v += __shfl_xor(v, 32);
    ws[qs] = v;
  }

  // ---- 2-stage combine: waves 4-7 write, waves 0-3 add in place ----
  if (w >= 4) {
    if (lane < 16) {
      wsh[w - 4][l15] = ws[0];
      wsh[w - 4][16 + l15] = ws[1];
    }
#pragma unroll
    for (int qs = 0; qs < 2; ++qs)
#pragma unroll
      for (int nt = 0; nt < 4; ++nt)
        *(float4*)&osh[w - 4][qs * 16 + l15][nt * 16 + 4 * g] =
            *(const float4*)&o[qs][nt];
  }
  __syncthreads();
  if (w < 4) {
    if (lane < 16) {
      wsh[w][l15] += ws[0];
      wsh[w][16 + l15] += ws[1];
    }
#pragma unroll
    for (int qs = 0; qs < 2; ++qs)
#pragma unroll
      for (int nt = 0; nt < 4; ++nt) {
        float4 v = *(const float4*)&osh[w][qs * 16 + l15][nt * 16 + 4 * g];
        v.x += o[qs][nt][0]; v.y += o[qs][nt][1];
        v.z += o[qs][nt][2]; v.w += o[qs][nt][3];
        *(float4*)&osh[w][qs * 16 + l15][nt * 16 + 4 * g] = v;
      }
  }
  __syncthreads();

  // ---- epilogue: sum 4 slices, divide, store fp32 (coalesced) ----
  {
    const int q = t >> 4, c4 = t & 15;      // 32q x 16 col4 = 512 items
    float4 acc = *(const float4*)&osh[0][q][c4 * 4];
    float wsr = wsh[0][q];
#pragma unroll
    for (int ww = 1; ww < 4; ++ww) {
      const float4 v = *(const float4*)&osh[ww][q][c4 * 4];
      acc.x += v.x; acc.y += v.y; acc.z += v.z; acc.w += v.w;
      wsr += wsh[ww][q];
    }
    const float inv = 1.0f / wsr;
    float4 rv = make_float4(acc.x * inv, acc.y * inv, acc.z * inv, acc.w * inv);
    *(float4*)&out[((size_t)(b * T_ + q0 + q)) * H_ + c4 * 4] = rv;
  }
}

extern "C" void kernel_launch(void* const* d_in, const int* in_sizes, int n_in,
                              void* d_out, int out_size, void* d_ws, size_t ws_size,
                              hipStream_t stream) {
  (void)in_sizes; (void)n_in; (void)out_size; (void)ws_size;
  const float* x  = (const float*)d_in[0];
  const float* wq = (const float*)d_in[1];
  const float* wk = (const float*)d_in[2];
  const float* wv = (const float*)d_in[3];

  char* ws = (char*)d_ws;
  short* wtf = (short*)(ws);                       // 384 KB
  short* Qb  = (short*)(ws + 0x0060000);           // 2 MB
  short* Kb  = (short*)(ws + 0x0260000);           // 2 MB
  short* Vt  = (short*)(ws + 0x0460000);           // 2 MB
  short* Kf  = (short*)(ws + 0x0660000);           // 2 MB frag-major
  short* Vf  = (short*)(ws + 0x0860000);           // 2 MB frag-major
  float* outp = (float*)d_out;

  wtconv_kernel<<<96, 256, 0, stream>>>(wq, wk, wv, wtf);
  proj_kernel<<<(B_ * T_) / 32, 256, 0, stream>>>(x, wtf, Qb, Kb, Vt);
  repack_kernel<<<dim3(T_ / 32, B_), 256, 0, stream>>>(Kb, Vt, Kf, Vf);
  attn_fused_kernel<<<512, 512, 0, stream>>>(Qb, Kf, Vf, outp);
}

// Round 28
// 64.528 us; speedup vs baseline: 1.2132x; 1.2132x over previous
//
#include <hip/hip_runtime.h>
#include <hip/hip_bf16.h>
#include <math.h>

#define B_ 4
#define T_ 4096
#define E_ 1024
#define H_ 64
#define KFB (T_ * H_)   // shorts per batch in Kf/Vf (fragment-major)
#define PRJ_RS 1048  // LDS row stride in shorts (2096B): 2-way banks, 16B-aligned

using bf16x8 = __attribute__((ext_vector_type(8))) short;
using f32x4  = __attribute__((ext_vector_type(4))) float;

__device__ inline short f2bf_rn(float f) {
  return (short)((__builtin_bit_cast(unsigned, f) + 0x8000u) >> 16);
}
__device__ inline unsigned pack2(float a, float b) {
  const unsigned ua = __builtin_bit_cast(unsigned, a) + 0x8000u;
  const unsigned ub = __builtin_bit_cast(unsigned, b) + 0x8000u;
  return (ua >> 16) | (ub & 0xFFFF0000u);
}
__device__ inline float bf2f(short s) {
  unsigned u = ((unsigned)(unsigned short)s) << 16;
  return __builtin_bit_cast(float, u);
}

// ---------- wt fragment-major: wtf[n][ks][lane][8] = W[32ks+8g+e][(n&3)*16+l15]
__global__ __launch_bounds__(256)
void wtconv_kernel(const float* __restrict__ wq, const float* __restrict__ wk,
                   const float* __restrict__ wv, short* __restrict__ wtf) {
  const int t = threadIdx.x;
  const int lane = t & 63, g = lane >> 4, l15 = lane & 15;
  const int ks = (blockIdx.x & 7) * 4 + (t >> 6);
  const int n = blockIdx.x >> 3;           // 0..11
  const float* W = (n < 4) ? wq : (n < 8) ? wk : wv;
  const int h = (n & 3) * 16 + l15;
  const int kbase = 32 * ks + 8 * g;
  bf16x8 v;
#pragma unroll
  for (int e = 0; e < 8; ++e) v[e] = f2bf_rn(W[(size_t)(kbase + e) * H_ + h]);
  *(bf16x8*)&wtf[((size_t)(n * 32 + ks) * 64 + lane) * 8] = v;
}

// ---------- QKV projection v8: 32q blocks, 8 waves = (k-half x col-triple) ----
// Wave w computes 6 partial accs over K-half (w>>2)*512 (16 steps). Pairs
// (w, w+4) reduce through LDS (xs reused as scratch after a sync). 2 blocks/CU
// but 16 waves/CU = 4 waves/SIMD. Best measured proj config (round 24).
__global__ __launch_bounds__(512, 4)
void proj_kernel(const float* __restrict__ x, const short* __restrict__ wtf,
                 short* __restrict__ Qb, short* __restrict__ Kb,
                 short* __restrict__ Vt) {
  __shared__ short xs[32 * PRJ_RS];
  const int q0 = blockIdx.x * 32;
  const int t = threadIdx.x;
  {
    const float4* xsrc = (const float4*)(x + (size_t)q0 * E_);
#pragma unroll
    for (int j = 0; j < 16; ++j) {
      const int i = t + 512 * j;          // 8192 float4s total
      const int row = i >> 8, col4 = i & 255;
      const float4 v = xsrc[i];
      uint2 u;
      u.x = pack2(v.x, v.y);
      u.y = pack2(v.z, v.w);
      *(uint2*)&xs[row * PRJ_RS + col4 * 4] = u;
    }
  }
  __syncthreads();
  const int w = t >> 6, lane = t & 63, g = lane >> 4, l15 = lane & 15;
  const int kh = w >> 2, cw = w & 3;
  f32x4 acc[6] = {{0,0,0,0},{0,0,0,0},{0,0,0,0},{0,0,0,0},{0,0,0,0},{0,0,0,0}};
  const short* xr0 = &xs[l15 * PRJ_RS + 8 * g];
  const short* xr1 = &xs[(16 + l15) * PRJ_RS + 8 * g];
  const int ks0 = kh * 16;
#pragma unroll 4
  for (int ks = ks0; ks < ks0 + 16; ++ks) {
    const bf16x8 av0 = *(const bf16x8*)(xr0 + ks * 32);
    const bf16x8 av1 = *(const bf16x8*)(xr1 + ks * 32);
    const short* wp = wtf + ((size_t)(cw * 3 * 32 + ks) * 64 + lane) * 8;
#pragma unroll
    for (int n = 0; n < 3; ++n) {
      const bf16x8 bfr = *(const bf16x8*)(wp + (size_t)n * 32 * 64 * 8);
      acc[n]     = __builtin_amdgcn_mfma_f32_16x16x32_bf16(av0, bfr, acc[n], 0, 0, 0);
      acc[3 + n] = __builtin_amdgcn_mfma_f32_16x16x32_bf16(av1, bfr, acc[3 + n], 0, 0, 0);
    }
  }
  // ---- pair reduce: waves 4-7 write partials into xs-scratch, 0-3 add ----
  __syncthreads();                          // all xs reads done
  float* red = (float*)xs;                  // [4 waves][6 accs][64 lanes][4]
  if (kh == 1) {
#pragma unroll
    for (int n = 0; n < 6; ++n)
      *(float4*)&red[((cw * 6 + n) * 64 + lane) * 4] = *(const float4*)&acc[n];
  }
  __syncthreads();
  if (kh == 0) {
#pragma unroll
    for (int n = 0; n < 6; ++n) {
      const float4 v = *(const float4*)&red[((cw * 6 + n) * 64 + lane) * 4];
      acc[n][0] += v.x; acc[n][1] += v.y; acc[n][2] += v.z; acc[n][3] += v.w;
    }
#pragma unroll
    for (int sub = 0; sub < 2; ++sub) {
#pragma unroll
      for (int n = 0; n < 3; ++n) {
        const int ntg = cw * 3 + n;
        const int mat = ntg >> 2;
        const int h = (ntg & 3) * 16 + l15;
#pragma unroll
        for (int r = 0; r < 4; ++r) {
          const int q = q0 + sub * 16 + 4 * g + r;
          const short v = f2bf_rn(acc[3 * sub + n][r]);
          if (mat == 0)      Qb[(size_t)q * H_ + h] = v;
          else if (mat == 1) Kb[(size_t)q * H_ + h] = v;
          else               Vt[((size_t)(q >> 12) * H_ + h) * T_ + (q & (T_ - 1))] = v;
        }
      }
    }
  }
}

// ---------- repack K,V into fragment-major Kf, Vf ----------
__global__ __launch_bounds__(256)
void repack_kernel(const short* __restrict__ Kb, const short* __restrict__ Vt,
                   short* __restrict__ Kf, short* __restrict__ Vf) {
  const int s = blockIdx.x, b = blockIdx.y;
  const int t = threadIdx.x;
  const int lane = t & 63, g = lane >> 4, l15 = lane & 15, slot = t >> 6;
  const int sig = ((l15 >> 2) << 3) + (l15 & 3);
  const size_t dst = ((size_t)b * KFB) + (((size_t)s * 4 + slot) * 64 + lane) * 8;
  const int key = 32 * s + sig + 4 * (slot >> 1);
  const int colK = (slot & 1) * 32 + 8 * g;
  *(bf16x8*)&Kf[dst] =
      *(const bf16x8*)&Kb[((size_t)b * T_ + key) * H_ + colK];
  *(bf16x8*)&Vf[dst] =
      *(const bf16x8*)&Vt[((size_t)b * H_ + slot * 16 + l15) * T_ + 32 * s + 8 * g];
}

// ---------- fused attention v9: complementary-pair grid + phase-1 2-wide -----
__global__ __launch_bounds__(512, 4)
void attn_fused_kernel(const short* __restrict__ Qb, const short* __restrict__ Kf,
                       const short* __restrict__ Vf, float* __restrict__ out) {
  __shared__ float osh[4][32][68];
  __shared__ float zsh[8][32];
  __shared__ float wsh[4][32];
  const int i = blockIdx.x;                 // 0..511
  const int hi = i >> 8;                    // 0/1
  const int b = (i & 1) | (hi << 1);        // 0..3
  const int j = (i >> 1) & 127;
  const int qt = hi ? j : 127 - j;          // i and i+256: complementary qt
  const int q0 = qt * 32;

  const int t = threadIdx.x;
  const int w = t >> 6, lane = t & 63, g = lane >> 4, l15 = lane & 15;
  const short* Qp = Qb + (size_t)b * T_ * H_;
  const short* kfB = Kf + (size_t)b * KFB;
  const short* vfB = Vf + (size_t)b * KFB;
  const size_t lo8 = (size_t)lane * 8;

  bf16x8 aq[2][2];
#pragma unroll
  for (int qs = 0; qs < 2; ++qs)
#pragma unroll
    for (int h = 0; h < 2; ++h)
      aq[qs][h] = *(const bf16x8*)&Qp[(size_t)(q0 + qs*16 + l15) * H_ + h*32 + 8*g];

  // ---- phase 1: Z over all keys, 2 chunks per body (wave stride 512) ----
  float z[2] = {0.f, 0.f};
  for (int kt = w * 32; kt < T_; kt += 512) {
    const short* ka = kfB + ((size_t)(kt >> 5) * 2048) + lo8;
    const short* kb2 = kfB + ((size_t)((kt + 256) >> 5) * 2048) + lo8;
    const bf16x8 a00 = *(const bf16x8*)(ka);
    const bf16x8 a01 = *(const bf16x8*)(ka + 512);
    const bf16x8 a10 = *(const bf16x8*)(ka + 1024);
    const bf16x8 a11 = *(const bf16x8*)(ka + 1536);
    const bf16x8 b00 = *(const bf16x8*)(kb2);
    const bf16x8 b01 = *(const bf16x8*)(kb2 + 512);
    const bf16x8 b10 = *(const bf16x8*)(kb2 + 1024);
    const bf16x8 b11 = *(const bf16x8*)(kb2 + 1536);
    f32x4 sA0 = {0,0,0,0}, sA1 = {0,0,0,0}, sA2 = {0,0,0,0}, sA3 = {0,0,0,0};
    f32x4 sB0 = {0,0,0,0}, sB1 = {0,0,0,0}, sB2 = {0,0,0,0}, sB3 = {0,0,0,0};
    sA0 = __builtin_amdgcn_mfma_f32_16x16x32_bf16(a00, aq[0][0], sA0, 0,0,0);
    sA0 = __builtin_amdgcn_mfma_f32_16x16x32_bf16(a01, aq[0][1], sA0, 0,0,0);
    sA1 = __builtin_amdgcn_mfma_f32_16x16x32_bf16(a10, aq[0][0], sA1, 0,0,0);
    sA1 = __builtin_amdgcn_mfma_f32_16x16x32_bf16(a11, aq[0][1], sA1, 0,0,0);
    sA2 = __builtin_amdgcn_mfma_f32_16x16x32_bf16(a00, aq[1][0], sA2, 0,0,0);
    sA2 = __builtin_amdgcn_mfma_f32_16x16x32_bf16(a01, aq[1][1], sA2, 0,0,0);
    sA3 = __builtin_amdgcn_mfma_f32_16x16x32_bf16(a10, aq[1][0], sA3, 0,0,0);
    sA3 = __builtin_amdgcn_mfma_f32_16x16x32_bf16(a11, aq[1][1], sA3, 0,0,0);
    sB0 = __builtin_amdgcn_mfma_f32_16x16x32_bf16(b00, aq[0][0], sB0, 0,0,0);
    sB0 = __builtin_amdgcn_mfma_f32_16x16x32_bf16(b01, aq[0][1], sB0, 0,0,0);
    sB1 = __builtin_amdgcn_mfma_f32_16x16x32_bf16(b10, aq[0][0], sB1, 0,0,0);
    sB1 = __builtin_amdgcn_mfma_f32_16x16x32_bf16(b11, aq[0][1], sB1, 0,0,0);
    sB2 = __builtin_amdgcn_mfma_f32_16x16x32_bf16(b00, aq[1][0], sB2, 0,0,0);
    sB2 = __builtin_amdgcn_mfma_f32_16x16x32_bf16(b01, aq[1][1], sB2, 0,0,0);
    sB3 = __builtin_amdgcn_mfma_f32_16x16x32_bf16(b10, aq[1][0], sB3, 0,0,0);
    sB3 = __builtin_amdgcn_mfma_f32_16x16x32_bf16(b11, aq[1][1], sB3, 0,0,0);
#pragma unroll
    for (int r = 0; r < 4; ++r) {
      z[0] += __expf(sA0[r] * 0.125f) + __expf(sA1[r] * 0.125f) +
              __expf(sB0[r] * 0.125f) + __expf(sB1[r] * 0.125f);
      z[1] += __expf(sA2[r] * 0.125f) + __expf(sA3[r] * 0.125f) +
              __expf(sB2[r] * 0.125f) + __expf(sB3[r] * 0.125f);
    }
  }
#pragma unroll
  for (int qs = 0; qs < 2; ++qs) {
    float v = z[qs];
    v += __shfl_xor(v, 16);
    v += __shfl_xor(v, 32);
    z[qs] = v;
  }
  if (lane < 16) {
    zsh[w][l15] = z[0];
    zsh[w][16 + l15] = z[1];
  }
  __syncthreads();
  float zinv[2];
#pragma unroll
  for (int qs = 0; qs < 2; ++qs) {
    float zsum = 0.f;
#pragma unroll
    for (int ww = 0; ww < 8; ++ww) zsum += zsh[ww][qs * 16 + l15];
    zinv[qs] = 1.0f / zsum;
  }

  // ---- phase 2: causal keys, wave stride 256 ----
  f32x4 o[2][4] = {{{0,0,0,0},{0,0,0,0},{0,0,0,0},{0,0,0,0}},
                   {{0,0,0,0},{0,0,0,0},{0,0,0,0},{0,0,0,0}}};
  float ws[2] = {0.f, 0.f};
  const int kend = q0 + 32;
  for (int kt = w * 32; kt < kend; kt += 256) {
    const size_t sb = ((size_t)(kt >> 5) * 2048) + lo8;
    const short* kb = kfB + sb;
    const bf16x8 ak00 = *(const bf16x8*)(kb);
    const bf16x8 ak01 = *(const bf16x8*)(kb + 512);
    const bf16x8 ak10 = *(const bf16x8*)(kb + 1024);
    const bf16x8 ak11 = *(const bf16x8*)(kb + 1536);
    const short* vb = vfB + sb;
    const bf16x8 av0 = *(const bf16x8*)(vb);
    const bf16x8 av1 = *(const bf16x8*)(vb + 512);
    const bf16x8 av2 = *(const bf16x8*)(vb + 1024);
    const bf16x8 av3 = *(const bf16x8*)(vb + 1536);

    bf16x8 wb[2];
    if (kt + 31 < q0) {                     // interior: all keys < all q
#pragma unroll
      for (int qs = 0; qs < 2; ++qs) {
        f32x4 sA = {0,0,0,0}, sB = {0,0,0,0};
        sA = __builtin_amdgcn_mfma_f32_16x16x32_bf16(ak00, aq[qs][0], sA, 0,0,0);
        sA = __builtin_amdgcn_mfma_f32_16x16x32_bf16(ak01, aq[qs][1], sA, 0,0,0);
        sB = __builtin_amdgcn_mfma_f32_16x16x32_bf16(ak10, aq[qs][0], sB, 0,0,0);
        sB = __builtin_amdgcn_mfma_f32_16x16x32_bf16(ak11, aq[qs][1], sB, 0,0,0);
        const float zi = zinv[qs];
        float wsl = 0.f;
#pragma unroll
        for (int r = 0; r < 4; ++r) {
          const float w0 = __expf(__expf(sA[r] * 0.125f) * zi);
          const float w1 = __expf(__expf(sB[r] * 0.125f) * zi);
          wsl += w0 + w1;
          wb[qs][r] = f2bf_rn(w0);
          wb[qs][4 + r] = f2bf_rn(w1);
        }
        ws[qs] += wsl;
      }
    } else {                                // diagonal: per-element mask
#pragma unroll
      for (int qs = 0; qs < 2; ++qs) {
        f32x4 sA = {0,0,0,0}, sB = {0,0,0,0};
        sA = __builtin_amdgcn_mfma_f32_16x16x32_bf16(ak00, aq[qs][0], sA, 0,0,0);
        sA = __builtin_amdgcn_mfma_f32_16x16x32_bf16(ak01, aq[qs][1], sA, 0,0,0);
        sB = __builtin_amdgcn_mfma_f32_16x16x32_bf16(ak10, aq[qs][0], sB, 0,0,0);
        sB = __builtin_amdgcn_mfma_f32_16x16x32_bf16(ak11, aq[qs][1], sB, 0,0,0);
        const int qg = q0 + qs * 16 + l15;
        const float zi = zinv[qs];
        float wsl = 0.f;
#pragma unroll
        for (int r = 0; r < 4; ++r) {
          const int key0 = kt + 8 * g + r;
          const float w0 = (key0     <= qg) ? __expf(__expf(sA[r] * 0.125f) * zi) : 0.f;
          const float w1 = (key0 + 4 <= qg) ? __expf(__expf(sB[r] * 0.125f) * zi) : 0.f;
          wsl += w0 + w1;
          wb[qs][r] = f2bf_rn(w0);
          wb[qs][4 + r] = f2bf_rn(w1);
        }
        ws[qs] += wsl;
      }
    }
    o[0][0] = __builtin_amdgcn_mfma_f32_16x16x32_bf16(av0, wb[0], o[0][0], 0,0,0);
    o[0][1] = __builtin_amdgcn_mfma_f32_16x16x32_bf16(av1, wb[0], o[0][1], 0,0,0);
    o[0][2] = __builtin_amdgcn_mfma_f32_16x16x32_bf16(av2, wb[0], o[0][2], 0,0,0);
    o[0][3] = __builtin_amdgcn_mfma_f32_16x16x32_bf16(av3, wb[0], o[0][3], 0,0,0);
    o[1][0] = __builtin_amdgcn_mfma_f32_16x16x32_bf16(av0, wb[1], o[1][0], 0,0,0);
    o[1][1] = __builtin_amdgcn_mfma_f32_16x16x32_bf16(av1, wb[1], o[1][1], 0,0,0);
    o[1][2] = __builtin_amdgcn_mfma_f32_16x16x32_bf16(av2, wb[1], o[1][2], 0,0,0);
    o[1][3] = __builtin_amdgcn_mfma_f32_16x16x32_bf16(av3, wb[1], o[1][3], 0,0,0);
  }

#pragma unroll
  for (int qs = 0; qs < 2; ++qs) {
    float v = ws[qs];
    v += __shfl_xor(v, 16);
    v += __shfl_xor(v, 32);
    ws[qs] = v;
  }

  // ---- 2-stage combine: waves 4-7 write, waves 0-3 add in place ----
  if (w >= 4) {
    if (lane < 16) {
      wsh[w - 4][l15] = ws[0];
      wsh[w - 4][16 + l15] = ws[1];
    }
#pragma unroll
    for (int qs = 0; qs < 2; ++qs)
#pragma unroll
      for (int nt = 0; nt < 4; ++nt)
        *(float4*)&osh[w - 4][qs * 16 + l15][nt * 16 + 4 * g] =
            *(const float4*)&o[qs][nt];
  }
  __syncthreads();
  if (w < 4) {
    if (lane < 16) {
      wsh[w][l15] += ws[0];
      wsh[w][16 + l15] += ws[1];
    }
#pragma unroll
    for (int qs = 0; qs < 2; ++qs)
#pragma unroll
      for (int nt = 0; nt < 4; ++nt) {
        float4 v = *(const float4*)&osh[w][qs * 16 + l15][nt * 16 + 4 * g];
        v.x += o[qs][nt][0]; v.y += o[qs][nt][1];
        v.z += o[qs][nt][2]; v.w += o[qs][nt][3];
        *(float4*)&osh[w][qs * 16 + l15][nt * 16 + 4 * g] = v;
      }
  }
  __syncthreads();

  // ---- epilogue: sum 4 slices, divide, store fp32 (coalesced) ----
  {
    const int q = t >> 4, c4 = t & 15;      // 32q x 16 col4 = 512 items
    float4 acc = *(const float4*)&osh[0][q][c4 * 4];
    float wsr = wsh[0][q];
#pragma unroll
    for (int ww = 1; ww < 4; ++ww) {
      const float4 v = *(const float4*)&osh[ww][q][c4 * 4];
      acc.x += v.x; acc.y += v.y; acc.z += v.z; acc.w += v.w;
      wsr += wsh[ww][q];
    }
    const float inv = 1.0f / wsr;
    float4 rv = make_float4(acc.x * inv, acc.y * inv, acc.z * inv, acc.w * inv);
    *(float4*)&out[((size_t)(b * T_ + q0 + q)) * H_ + c4 * 4] = rv;
  }
}

extern "C" void kernel_launch(void* const* d_in, const int* in_sizes, int n_in,
                              void* d_out, int out_size, void* d_ws, size_t ws_size,
                              hipStream_t stream) {
  (void)in_sizes; (void)n_in; (void)out_size; (void)ws_size;
  const float* x  = (const float*)d_in[0];
  const float* wq = (const float*)d_in[1];
  const float* wk = (const float*)d_in[2];
  const float* wv = (const float*)d_in[3];

  char* ws = (char*)d_ws;
  short* wtf = (short*)(ws);                       // 384 KB
  short* Qb  = (short*)(ws + 0x0060000);           // 2 MB
  short* Kb  = (short*)(ws + 0x0260000);           // 2 MB
  short* Vt  = (short*)(ws + 0x0460000);           // 2 MB
  short* Kf  = (short*)(ws + 0x0660000);           // 2 MB frag-major
  short* Vf  = (short*)(ws + 0x0860000);           // 2 MB frag-major
  float* outp = (float*)d_out;

  wtconv_kernel<<<96, 256, 0, stream>>>(wq, wk, wv, wtf);
  proj_kernel<<<(B_ * T_) / 32, 512, 0, stream>>>(x, wtf, Qb, Kb, Vt);
  repack_kernel<<<dim3(T_ / 32, B_), 256, 0, stream>>>(Kb, Vt, Kf, Vf);
  attn_fused_kernel<<<512, 512, 0, stream>>>(Qb, Kf, Vf, outp);
}